// Round 1
// baseline (351.981 us; speedup 1.0000x reference)
//
#include <hip/hip_runtime.h>
#include <math.h>

// SimpleGCN: h1 = relu(GCN(x,W1,b1)); h2 = relu(GCN(h1,W2,b2));
// g = mean(h2, axis=0); out = (g@Wr + br) -> 128 fp32.
// GCN(x,W,b)[d] = dinv[d]*( sum_{s in N(d)} y[s] + y[d] ) + b,
//   where y = dinv * (x@W), dinv[i] = (1+indeg[i])^-0.5.
// CSR built once per call (same graph both layers). No float atomics in
// aggregation; hidden=64 == one wave -> lane==feature, coalesced row gathers.

#define HID 64

__global__ void k_zero(int* __restrict__ counts, float* __restrict__ g, int n) {
    int i = blockIdx.x * blockDim.x + threadIdx.x;
    if (i < n) counts[i] = 0;
    if (i < HID) g[i] = 0.f;
}

__global__ void k_hist(const int* __restrict__ dst, int* __restrict__ counts, int E) {
    int e = blockIdx.x * blockDim.x + threadIdx.x;
    if (e < E) atomicAdd(&counts[dst[e]], 1);
}

__global__ void k_blocksum(const int* __restrict__ counts, int* __restrict__ bsum, int n) {
    __shared__ int sm[256];
    int t = threadIdx.x;
    int i = blockIdx.x * 256 + t;
    sm[t] = (i < n) ? counts[i] : 0;
    __syncthreads();
    for (int off = 128; off > 0; off >>= 1) {
        if (t < off) sm[t] += sm[t + off];
        __syncthreads();
    }
    if (t == 0) bsum[blockIdx.x] = sm[0];
}

// exclusive scan of nb (<=256) block sums, single block
__global__ void k_scanb(const int* __restrict__ bsum, int* __restrict__ boff, int nb) {
    __shared__ int sm[256];
    int t = threadIdx.x;
    int v = (t < nb) ? bsum[t] : 0;
    sm[t] = v;
    __syncthreads();
    for (int off = 1; off < 256; off <<= 1) {
        int x = (t >= off) ? sm[t - off] : 0;
        __syncthreads();
        sm[t] += x;
        __syncthreads();
    }
    if (t < nb) boff[t] = sm[t] - v;  // exclusive
}

__global__ void k_finalize(const int* __restrict__ counts, const int* __restrict__ boff,
                           int* __restrict__ offsets, int* __restrict__ cursor,
                           float* __restrict__ dinv, int n, int E) {
    __shared__ int sm[256];
    int t = threadIdx.x;
    int i = blockIdx.x * 256 + t;
    int v = (i < n) ? counts[i] : 0;
    sm[t] = v;
    __syncthreads();
    for (int off = 1; off < 256; off <<= 1) {
        int x = (t >= off) ? sm[t - off] : 0;
        __syncthreads();
        sm[t] += x;
        __syncthreads();
    }
    if (i < n) {
        int excl = boff[blockIdx.x] + sm[t] - v;
        offsets[i] = excl;
        cursor[i] = excl;
        dinv[i] = 1.0f / sqrtf((float)(v + 1));  // deg includes self-loop
        if (i == n - 1) offsets[n] = E;
    }
}

__global__ void k_scatter(const int* __restrict__ src, const int* __restrict__ dst,
                          int* __restrict__ cursor, int* __restrict__ csr_src, int E) {
    int e = blockIdx.x * blockDim.x + threadIdx.x;
    if (e < E) {
        int pos = atomicAdd(&cursor[dst[e]], 1);
        csr_src[pos] = src[e];
    }
}

// Y[i,:] = dinv[i] * (X[i,:] @ W),  W is 64x64 staged in LDS, 4 rows/block
__global__ __launch_bounds__(256) void k_gemm_scale(const float* __restrict__ X,
                                                    const float* __restrict__ W,
                                                    const float* __restrict__ dinv,
                                                    float* __restrict__ Y, int n) {
    __shared__ float Ws[64 * 64];
    __shared__ float xs[4][64];
    int t = threadIdx.x, w = t >> 6, f = t & 63;
    const float4* W4 = (const float4*)W;
    float4* Ws4 = (float4*)Ws;
#pragma unroll
    for (int j = 0; j < 4; j++) Ws4[t + 256 * j] = W4[t + 256 * j];
    int r = blockIdx.x * 4 + w;
    float dv = 0.f;
    if (r < n) {
        xs[w][f] = X[(size_t)r * 64 + f];
        dv = dinv[r];
    }
    __syncthreads();
    if (r < n) {
        float acc = 0.f;
#pragma unroll
        for (int k = 0; k < 64; k++) acc += xs[w][k] * Ws[k * 64 + f];
        Y[(size_t)r * 64 + f] = dv * acc;
    }
}

// one wave per node, lane = feature; neighbor rows are coalesced 256B loads
__global__ __launch_bounds__(256) void k_aggregate(const float* __restrict__ Y,
                                                   const float* __restrict__ dinv,
                                                   const float* __restrict__ bias,
                                                   const int* __restrict__ offsets,
                                                   const int* __restrict__ csr_src,
                                                   float* __restrict__ H, int n) {
    int t = threadIdx.x, w = t >> 6, f = t & 63;
    int node = blockIdx.x * 4 + w;
    if (node >= n) return;
    int beg = offsets[node], end = offsets[node + 1];
    float acc = Y[(size_t)node * 64 + f];  // self-loop term
    int j = beg;
    for (; j + 1 < end; j += 2) {
        int s0 = csr_src[j], s1 = csr_src[j + 1];
        float a0 = Y[(size_t)s0 * 64 + f];
        float a1 = Y[(size_t)s1 * 64 + f];
        acc += a0 + a1;
    }
    if (j < end) {
        int s = csr_src[j];
        acc += Y[(size_t)s * 64 + f];
    }
    H[(size_t)node * 64 + f] = fmaxf(dinv[node] * acc + bias[f], 0.f);
}

__global__ void k_mean(const float* __restrict__ H, float* __restrict__ g, int n) {
    __shared__ float part[256];
    int t = threadIdx.x, w = t >> 6, f = t & 63;
    float local = 0.f;
    for (int r = blockIdx.x * 4 + w; r < n; r += gridDim.x * 4)
        local += H[(size_t)r * 64 + f];
    part[t] = local;
    __syncthreads();
    if (w == 0) {
        float tot = part[f] + part[64 + f] + part[128 + f] + part[192 + f];
        atomicAdd(&g[f], tot);
    }
}

__global__ void k_readout(const float* __restrict__ g, const float* __restrict__ Wr,
                          const float* __restrict__ br, float* __restrict__ out,
                          float invn) {
    __shared__ float gl[64];
    int t = threadIdx.x;
    if (t < 64) gl[t] = g[t] * invn;
    __syncthreads();
    float acc = br[t];
#pragma unroll
    for (int k = 0; k < 64; k++) acc += gl[k] * Wr[k * 128 + t];
    out[t] = acc;
}

extern "C" void kernel_launch(void* const* d_in, const int* in_sizes, int n_in,
                              void* d_out, int out_size, void* d_ws, size_t ws_size,
                              hipStream_t stream) {
    const float* x  = (const float*)d_in[0];
    const int*   ei = (const int*)d_in[1];   // int32 on device (JAX default x64-off)
    const float* W1 = (const float*)d_in[2];
    const float* b1 = (const float*)d_in[3];
    const float* W2 = (const float*)d_in[4];
    const float* b2 = (const float*)d_in[5];
    const float* Wr = (const float*)d_in[6];
    const float* br = (const float*)d_in[7];
    float* out = (float*)d_out;

    int n = in_sizes[0] / 64;   // 50000
    int E = in_sizes[1] / 2;    // 800000
    const int* src = ei;
    const int* dst = ei + E;

    // workspace layout (~30 MB)
    char* p = (char*)d_ws;
    float* y = (float*)p;      p += (size_t)n * 64 * sizeof(float);
    float* h = (float*)p;      p += (size_t)n * 64 * sizeof(float);
    float* dinv = (float*)p;   p += (size_t)n * sizeof(float);
    float* g = (float*)p;      p += 64 * sizeof(float);
    int* counts = (int*)p;     p += (size_t)n * sizeof(int);
    int* offsets = (int*)p;    p += (size_t)(n + 1) * sizeof(int);
    int* cursor = (int*)p;     p += (size_t)n * sizeof(int);
    int* bsum = (int*)p;       p += 256 * sizeof(int);
    int* boff = (int*)p;       p += 256 * sizeof(int);
    int* csr_src = (int*)p;    p += (size_t)E * sizeof(int);

    int nb = (n + 255) / 256;  // 196 (<=256 required by k_scanb)
    int eb = (E + 255) / 256;
    int gb = (n + 3) / 4;

    k_zero<<<nb, 256, 0, stream>>>(counts, g, n);
    k_hist<<<eb, 256, 0, stream>>>(dst, counts, E);
    k_blocksum<<<nb, 256, 0, stream>>>(counts, bsum, n);
    k_scanb<<<1, 256, 0, stream>>>(bsum, boff, nb);
    k_finalize<<<nb, 256, 0, stream>>>(counts, boff, offsets, cursor, dinv, n, E);
    k_scatter<<<eb, 256, 0, stream>>>(src, dst, cursor, csr_src, E);

    k_gemm_scale<<<gb, 256, 0, stream>>>(x, W1, dinv, y, n);
    k_aggregate<<<gb, 256, 0, stream>>>(y, dinv, b1, offsets, csr_src, h, n);
    k_gemm_scale<<<gb, 256, 0, stream>>>(h, W2, dinv, y, n);
    k_aggregate<<<gb, 256, 0, stream>>>(y, dinv, b2, offsets, csr_src, h, n);

    k_mean<<<128, 256, 0, stream>>>(h, g, n);
    k_readout<<<1, 128, 0, stream>>>(g, Wr, br, out, 1.0f / (float)n);
}

// Round 2
// 274.863 us; speedup vs baseline: 1.2806x; 1.2806x over previous
//
#include <hip/hip_runtime.h>
#include <math.h>

// SimpleGCN: h1 = relu(GCN(x,W1,b1)); h2 = relu(GCN(h1,W2,b2));
// g = mean(h2, axis=0); out = (g@Wr + br) -> 128 fp32.
// GCN(x,W,b)[d] = dinv[d]*( sum_{s in N(d)} y[s] + y[d] ) + b,
//   y = dinv * (x@W), dinv[i] = (1+indeg[i])^-0.5.
// CSR built once per call (shared by both layers). Aggregation: one wave per
// node, lane==feature, unroll-8 predicated gathers for MLP (R1 was
// latency-bound at 23% HBM). Layer-2 aggregate fuses ReLU+block-partial mean
// (no H write). GEMM: 4 rows/wave so one LDS W-read feeds 4 FMAs.

#define HID 64

__global__ void k_hist(const int* __restrict__ dst, int* __restrict__ counts, int E) {
    int e = blockIdx.x * blockDim.x + threadIdx.x;
    if (e < E) atomicAdd(&counts[dst[e]], 1);
}

__global__ void k_blocksum(const int* __restrict__ counts, int* __restrict__ bsum, int n) {
    __shared__ int sm[256];
    int t = threadIdx.x;
    int i = blockIdx.x * 256 + t;
    sm[t] = (i < n) ? counts[i] : 0;
    __syncthreads();
    for (int off = 128; off > 0; off >>= 1) {
        if (t < off) sm[t] += sm[t + off];
        __syncthreads();
    }
    if (t == 0) bsum[blockIdx.x] = sm[0];
}

// exclusive scan of nb (<=256) block sums, single block
__global__ void k_scanb(const int* __restrict__ bsum, int* __restrict__ boff, int nb) {
    __shared__ int sm[256];
    int t = threadIdx.x;
    int v = (t < nb) ? bsum[t] : 0;
    sm[t] = v;
    __syncthreads();
    for (int off = 1; off < 256; off <<= 1) {
        int x = (t >= off) ? sm[t - off] : 0;
        __syncthreads();
        sm[t] += x;
        __syncthreads();
    }
    if (t < nb) boff[t] = sm[t] - v;  // exclusive
}

__global__ void k_finalize(const int* __restrict__ counts, const int* __restrict__ boff,
                           int* __restrict__ offsets, int* __restrict__ cursor,
                           float* __restrict__ dinv, int n, int E) {
    __shared__ int sm[256];
    int t = threadIdx.x;
    int i = blockIdx.x * 256 + t;
    int v = (i < n) ? counts[i] : 0;
    sm[t] = v;
    __syncthreads();
    for (int off = 1; off < 256; off <<= 1) {
        int x = (t >= off) ? sm[t - off] : 0;
        __syncthreads();
        sm[t] += x;
        __syncthreads();
    }
    if (i < n) {
        int excl = boff[blockIdx.x] + sm[t] - v;
        offsets[i] = excl;
        cursor[i] = excl;
        dinv[i] = 1.0f / sqrtf((float)(v + 1));  // deg includes self-loop
        if (i == n - 1) offsets[n] = E;
    }
}

__global__ void k_scatter(const int* __restrict__ src, const int* __restrict__ dst,
                          int* __restrict__ cursor, int* __restrict__ csr_src, int E) {
    int e = blockIdx.x * blockDim.x + threadIdx.x;
    if (e < E) {
        int pos = atomicAdd(&cursor[dst[e]], 1);
        csr_src[pos] = src[e];
    }
}

// Y[i,:] = dinv[i] * (X[i,:] @ W). 16 rows/block, 4 rows/wave: one LDS read
// of W[k][f] feeds 4 FMAs (R1 version was LDS-issue-bound at 1 read/FMA).
__global__ __launch_bounds__(256) void k_gemm_scale(const float* __restrict__ X,
                                                    const float* __restrict__ W,
                                                    const float* __restrict__ dinv,
                                                    float* __restrict__ Y, int n) {
    __shared__ float Ws[64 * 64];
    __shared__ float xs[16][64];
    int t = threadIdx.x, w = t >> 6, f = t & 63;
    const float4* W4 = (const float4*)W;
    float4* Ws4 = (float4*)Ws;
#pragma unroll
    for (int j = 0; j < 4; j++) Ws4[t + 256 * j] = W4[t + 256 * j];
    int r0 = blockIdx.x * 16;
#pragma unroll
    for (int i = 0; i < 4; i++) {
        int r = r0 + w * 4 + i;
        xs[w * 4 + i][f] = (r < n) ? X[(size_t)r * 64 + f] : 0.f;
    }
    __syncthreads();
    float acc[4] = {0.f, 0.f, 0.f, 0.f};
#pragma unroll 8
    for (int k = 0; k < 64; k++) {
        float wv = Ws[k * 64 + f];  // lanes hit 32 banks x2 -> conflict-free
#pragma unroll
        for (int i = 0; i < 4; i++) acc[i] += xs[w * 4 + i][k] * wv;  // LDS broadcast
    }
#pragma unroll
    for (int i = 0; i < 4; i++) {
        int r = r0 + w * 4 + i;
        if (r < n) Y[(size_t)r * 64 + f] = dinv[r] * acc[i];
    }
}

// One wave per node, lane = feature. Unroll-8 with clamped+predicated loads:
// 8 independent 256B row gathers in flight (R1 had ~2 -> latency-bound).
// POOL=true: skip H store, emit per-block partial feature sums for the mean.
template <bool POOL>
__global__ __launch_bounds__(256) void k_aggregate(const float* __restrict__ Y,
                                                   const float* __restrict__ dinv,
                                                   const float* __restrict__ bias,
                                                   const int* __restrict__ offsets,
                                                   const int* __restrict__ csr_src,
                                                   float* __restrict__ H,
                                                   float* __restrict__ pbuf, int n) {
    __shared__ float sm[256];
    int t = threadIdx.x, w = t >> 6, f = t & 63;
    int node = blockIdx.x * 4 + w;
    bool valid = node < n;
    float hval = 0.f;
    if (valid) {
        int beg = offsets[node], end = offsets[node + 1];
        float acc = Y[(size_t)node * 64 + f];  // self-loop term
        for (int j = beg; j < end; j += 8) {
#pragma unroll
            for (int u = 0; u < 8; u++) {
                int jj = j + u;
                bool c = jj < end;
                int jc = c ? jj : beg;  // safe: loop entered => beg < end
                int s = csr_src[jc];
                float a = Y[(size_t)s * 64 + f];
                acc += c ? a : 0.f;
            }
        }
        hval = fmaxf(dinv[node] * acc + bias[f], 0.f);
        if (!POOL) H[(size_t)node * 64 + f] = hval;
    }
    if (POOL) {
        sm[t] = valid ? hval : 0.f;
        __syncthreads();
        if (w == 0) pbuf[(size_t)blockIdx.x * 64 + f] =
            sm[f] + sm[64 + f] + sm[128 + f] + sm[192 + f];
    }
}

__global__ void k_mean_final(const float* __restrict__ pbuf, float* __restrict__ g,
                             int nrows) {
    __shared__ float part[256];
    int t = threadIdx.x, w = t >> 6, f = t & 63;
    float local = 0.f;
    for (int r = blockIdx.x * 4 + w; r < nrows; r += gridDim.x * 4)
        local += pbuf[(size_t)r * 64 + f];
    part[t] = local;
    __syncthreads();
    if (w == 0) {
        float tot = part[f] + part[64 + f] + part[128 + f] + part[192 + f];
        atomicAdd(&g[f], tot);
    }
}

__global__ void k_readout(const float* __restrict__ g, const float* __restrict__ Wr,
                          const float* __restrict__ br, float* __restrict__ out,
                          float invn) {
    __shared__ float gl[64];
    int t = threadIdx.x;
    if (t < 64) gl[t] = g[t] * invn;
    __syncthreads();
    float acc = br[t];
#pragma unroll
    for (int k = 0; k < 64; k++) acc += gl[k] * Wr[k * 128 + t];
    out[t] = acc;
}

extern "C" void kernel_launch(void* const* d_in, const int* in_sizes, int n_in,
                              void* d_out, int out_size, void* d_ws, size_t ws_size,
                              hipStream_t stream) {
    const float* x  = (const float*)d_in[0];
    const int*   ei = (const int*)d_in[1];   // int32 on device (JAX x64 off)
    const float* W1 = (const float*)d_in[2];
    const float* b1 = (const float*)d_in[3];
    const float* W2 = (const float*)d_in[4];
    const float* b2 = (const float*)d_in[5];
    const float* Wr = (const float*)d_in[6];
    const float* br = (const float*)d_in[7];
    float* out = (float*)d_out;

    int n = in_sizes[0] / 64;   // 50000
    int E = in_sizes[1] / 2;    // 800000
    const int* src = ei;
    const int* dst = ei + E;

    // workspace layout (~30 MB)
    char* p = (char*)d_ws;
    float* y = (float*)p;      p += (size_t)n * 64 * sizeof(float);
    float* h = (float*)p;      p += (size_t)n * 64 * sizeof(float);
    float* dinv = (float*)p;   p += (size_t)n * sizeof(float);
    float* g = (float*)p;      p += 64 * sizeof(float);
    int* counts = (int*)p;     p += (size_t)n * sizeof(int);
    int* offsets = (int*)p;    p += (size_t)(n + 1) * sizeof(int);
    int* cursor = (int*)p;     p += (size_t)n * sizeof(int);
    int* bsum = (int*)p;       p += 256 * sizeof(int);
    int* boff = (int*)p;       p += 256 * sizeof(int);
    int* csr_src = (int*)p;    p += (size_t)E * sizeof(int);

    int nb = (n + 255) / 256;  // 196 (<=256 required by k_scanb)
    int eb = (E + 255) / 256;
    int gb = (n + 3) / 4;      // 12500 (one wave per node)

    hipMemsetAsync(counts, 0, (size_t)n * sizeof(int), stream);
    hipMemsetAsync(g, 0, 64 * sizeof(float), stream);
    k_hist<<<eb, 256, 0, stream>>>(dst, counts, E);
    k_blocksum<<<nb, 256, 0, stream>>>(counts, bsum, n);
    k_scanb<<<1, 256, 0, stream>>>(bsum, boff, nb);
    k_finalize<<<nb, 256, 0, stream>>>(counts, boff, offsets, cursor, dinv, n, E);
    k_scatter<<<eb, 256, 0, stream>>>(src, dst, cursor, csr_src, E);

    k_gemm_scale<<<(n + 15) / 16, 256, 0, stream>>>(x, W1, dinv, y, n);
    k_aggregate<false><<<gb, 256, 0, stream>>>(y, dinv, b1, offsets, csr_src, h, nullptr, n);
    k_gemm_scale<<<(n + 15) / 16, 256, 0, stream>>>(h, W2, dinv, y, n);
    // layer-2: h no longer needed afterwards -> reuse as per-block partial buf
    float* pbuf = h;
    k_aggregate<true><<<gb, 256, 0, stream>>>(y, dinv, b2, offsets, csr_src, nullptr, pbuf, n);

    k_mean_final<<<64, 256, 0, stream>>>(pbuf, g, gb);
    k_readout<<<1, 128, 0, stream>>>(g, Wr, br, out, 1.0f / (float)n);
}